// Round 8
// baseline (566.196 us; speedup 1.0000x reference)
//
#include <hip/hip_runtime.h>
#include <cstddef>

#define NPTS 500000
#define DF 64
#define NC 10000
#define BN_EPS 1e-5f

#define TPB 256
#define PTILE 64
#define NTILES ((NPTS + PTILE - 1) / PTILE)  // 7813
#define GBLK 768                             // GEMM grids: 3 blocks/CU (48KB)
#define SBLK 2048                            // streaming grids

// ---- order-preserving float<->uint encoding (for atomic max on floats) ----
__device__ __forceinline__ unsigned f2o(float f) {
  unsigned u = __float_as_uint(f);
  return (u & 0x80000000u) ? ~u : (u | 0x80000000u);
}
__device__ __forceinline__ float o2f(unsigned u) {
  return __uint_as_float((u & 0x80000000u) ? (u ^ 0x80000000u) : ~u);
}

// async global->LDS, 16B per lane. LDS dest is wave-uniform base + lane*16.
__device__ __forceinline__ void gload16(const float* g, float* l) {
  __builtin_amdgcn_global_load_lds(
      (const __attribute__((address_space(1))) void*)g,
      (__attribute__((address_space(3))) void*)l, 16, 0, 0);
}

// Stage one 64-point x tile (16 KB) into a linear LDS buffer via
// global_load_lds_dwordx4. PRE-SWIZZLED source: LDS 16B-slot (p, jb) receives
// x[p][(jb ^ (p>>2))*4 ..]; compute-side reads chunk j4 of row p at slot
// j4 ^ (p>>2) -> conflict-free, dest stays linear (rule 21).
__device__ __forceinline__ void stage_tile(float* xsbuf, const float* x,
                                           int pbase, int wave, int lane) {
#pragma unroll
  for (int i = 0; i < 4; ++i) {
    const int chunk = wave * 4 + i;       // 0..15, wave-uniform
    const int slot = chunk * 64 + lane;   // 16B slot id 0..1023
    const int p = slot >> 4;              // local point 0..63
    const int jb = slot & 15;             // 16B column block
    int gp = pbase + p;
    if (gp >= NPTS) gp = NPTS - 1;        // tail: safe garbage row
    const int jsrc = jb ^ (p >> 2);
    gload16(x + (size_t)gp * DF + jsrc * 4, xsbuf + chunk * 256);
  }
}

// ws layout (float/uint units):
// 0        : q_u     [NC*DF]   segment max of Q  (DEAD after g_kernel;
//                              region reused as attn[NPTS] by stats/apply)
// 640000   : mmax_u  [NC]      sortable-uint segment max of M
// 650000   : denom   [NC]      segment sum of exp
// 660000   : sums    [2*DF]    [sum h | sum h^2]
// 660128   : scale   [DF]
// 660192   : shift   [DF]
// 660256   : Mv      [NPTS]    M, then overwritten with e=exp(M-mmax)
// 1160256  : gtab    [NC*DF]   g_c = Wk^T q_c
// 1800256  : bdot    [NC]      b_c = bk . q_c
// raw v rows live in d_out until apply overwrites them with the result.

// ---------------------------------------------------------------------------
// Q projection (round-1-proven dbuf structure): q -> filtered atomicMax q_u.
// Thread (fg=tid&15, pg=tid>>4) owns features f0..f0+3 of points pg*4..+3.
// ---------------------------------------------------------------------------
__launch_bounds__(TPB, 3)
__global__ void q_kernel(const float* __restrict__ x,
                         const int* __restrict__ cluster,
                         const float* __restrict__ Wq,
                         const float* __restrict__ bq,
                         unsigned* __restrict__ q_u) {
  __shared__ float Wt[DF * DF];        // Wt[j][f]
  __shared__ float xs[2][PTILE * DF];  // double-buffered x tiles

  const int tid = threadIdx.x;
  const int lane = tid & 63;
  const int wave = tid >> 6;
  const int fg = tid & 15;
  const int pg = tid >> 4;
  const int f0 = fg * 4;

  {
    const int f = tid & 63;
    const int jb = (tid >> 6) * 16;
#pragma unroll
    for (int i = 0; i < 4; ++i) {
      float4 wr = *(const float4*)(Wq + f * DF + jb + i * 4);
      Wt[(jb + i * 4 + 0) * DF + f] = wr.x;
      Wt[(jb + i * 4 + 1) * DF + f] = wr.y;
      Wt[(jb + i * 4 + 2) * DF + f] = wr.z;
      Wt[(jb + i * 4 + 3) * DF + f] = wr.w;
    }
  }
  const float4 b4 = *(const float4*)(bq + f0);

  int t = blockIdx.x;
  stage_tile(xs[0], x, t * PTILE, wave, lane);
  asm volatile("s_waitcnt vmcnt(0) lgkmcnt(0)" ::: "memory");
  __builtin_amdgcn_s_barrier();
  asm volatile("" ::: "memory");

  int cur = 0;
  for (; t < NTILES; t += GBLK) {
    const int pbase = t * PTILE;
    stage_tile(xs[cur ^ 1], x, (t + GBLK) * PTILE, wave, lane);
    int4 c4;
    {
      const int cb = pbase + pg * 4;
      if (cb + 3 < NPTS) {
        c4 = *(const int4*)(cluster + cb);
      } else {
        c4.x = cluster[cb + 0 < NPTS ? cb + 0 : NPTS - 1];
        c4.y = cluster[cb + 1 < NPTS ? cb + 1 : NPTS - 1];
        c4.z = cluster[cb + 2 < NPTS ? cb + 2 : NPTS - 1];
        c4.w = cluster[cb + 3 < NPTS ? cb + 3 : NPTS - 1];
      }
    }
    asm volatile("" ::: "memory");

    float4 acc[4];
#pragma unroll
    for (int pp = 0; pp < 4; ++pp) acc[pp] = b4;
#pragma unroll 4
    for (int j4 = 0; j4 < 16; ++j4) {
      float4 wv[4];
#pragma unroll
      for (int e = 0; e < 4; ++e)
        wv[e] = *(const float4*)(Wt + (j4 * 4 + e) * DF + f0);
      const int xoff = (j4 ^ pg) * 4;
#pragma unroll
      for (int pp = 0; pp < 4; ++pp) {
        float4 xv = *(const float4*)(&xs[cur][(pg * 4 + pp) * DF + xoff]);
        acc[pp].x = fmaf(xv.x, wv[0].x, acc[pp].x);
        acc[pp].y = fmaf(xv.x, wv[0].y, acc[pp].y);
        acc[pp].z = fmaf(xv.x, wv[0].z, acc[pp].z);
        acc[pp].w = fmaf(xv.x, wv[0].w, acc[pp].w);
        acc[pp].x = fmaf(xv.y, wv[1].x, acc[pp].x);
        acc[pp].y = fmaf(xv.y, wv[1].y, acc[pp].y);
        acc[pp].z = fmaf(xv.y, wv[1].z, acc[pp].z);
        acc[pp].w = fmaf(xv.y, wv[1].w, acc[pp].w);
        acc[pp].x = fmaf(xv.z, wv[2].x, acc[pp].x);
        acc[pp].y = fmaf(xv.z, wv[2].y, acc[pp].y);
        acc[pp].z = fmaf(xv.z, wv[2].z, acc[pp].z);
        acc[pp].w = fmaf(xv.z, wv[2].w, acc[pp].w);
        acc[pp].x = fmaf(xv.w, wv[3].x, acc[pp].x);
        acc[pp].y = fmaf(xv.w, wv[3].y, acc[pp].y);
        acc[pp].z = fmaf(xv.w, wv[3].z, acc[pp].z);
        acc[pp].w = fmaf(xv.w, wv[3].w, acc[pp].w);
      }
    }

#pragma unroll
    for (int pp = 0; pp < 4; ++pp) {
      const int p = pbase + pg * 4 + pp;
      if (p < NPTS) {
        const int cc = (pp == 0) ? c4.x : (pp == 1) ? c4.y
                       : (pp == 2) ? c4.z : c4.w;
        unsigned* dst = q_u + (size_t)cc * DF + f0;
        // monotone q_u: stale read only under-reports -> filter is race-safe
        const uint4 curq = *(const uint4*)dst;
        const unsigned ex = f2o(acc[pp].x);
        const unsigned ey = f2o(acc[pp].y);
        const unsigned ez = f2o(acc[pp].z);
        const unsigned ew = f2o(acc[pp].w);
        if (ex > curq.x) atomicMax(dst + 0, ex);
        if (ey > curq.y) atomicMax(dst + 1, ey);
        if (ez > curq.z) atomicMax(dst + 2, ez);
        if (ew > curq.w) atomicMax(dst + 3, ew);
      }
    }

    asm volatile("s_waitcnt vmcnt(0)" ::: "memory");
    __builtin_amdgcn_s_barrier();
    asm volatile("" ::: "memory");
    cur ^= 1;
  }
}

// ---------------------------------------------------------------------------
// g-trick precompute: per cluster c, g_c = Wk^T q_c, b_c = bk . q_c.
// M_p = x_p . g_{c_p} + b_{c_p} (exact reassociation of q.(Wk x + bk)).
// ---------------------------------------------------------------------------
__global__ void g_kernel(const unsigned* __restrict__ q_u,
                         const float* __restrict__ Wk,
                         const float* __restrict__ bk,
                         float* __restrict__ gtab,
                         float* __restrict__ bdot) {
  const int lane = threadIdx.x & 63;
  const int wave = threadIdx.x >> 6;
  const int c = blockIdx.x * 4 + wave;
  if (c >= NC) return;
  const unsigned* qp = q_u + (size_t)c * DF;
  float acc = 0.f, bacc = 0.f;
#pragma unroll 8
  for (int f = 0; f < DF; ++f) {
    const float qf = o2f(qp[f]);             // broadcast within wave
    acc = fmaf(qf, Wk[f * DF + lane], acc);  // coalesced across lanes
    bacc = fmaf(qf, bk[f], bacc);
  }
  gtab[(size_t)c * DF + lane] = acc;
  if (lane == 0) bdot[c] = bacc;
}

// ---------------------------------------------------------------------------
// V projection + fused M: v -> out (raw f32), M = x.g[c]+b[c] computed from
// the x tile ALREADY IN LDS (one extra b128/point-chunk) + L2-resident gtab
// gather. Mv[p] = M, filtered atomicMax mmax_u. Kills the standalone 128MB
// mdot pass.
// ---------------------------------------------------------------------------
__launch_bounds__(TPB, 3)
__global__ void vm_kernel(const float* __restrict__ x,
                          const int* __restrict__ cluster,
                          const float* __restrict__ Wv,
                          const float* __restrict__ bv,
                          const float* __restrict__ gtab,
                          const float* __restrict__ bdot,
                          float* __restrict__ Mv,
                          unsigned* __restrict__ mmax_u,
                          float* __restrict__ out) {
  __shared__ float Wt[DF * DF];
  __shared__ float xs[2][PTILE * DF];

  const int tid = threadIdx.x;
  const int lane = tid & 63;
  const int wave = tid >> 6;
  const int fg = tid & 15;
  const int pg = tid >> 4;
  const int f0 = fg * 4;

  {
    const int f = tid & 63;
    const int jb = (tid >> 6) * 16;
#pragma unroll
    for (int i = 0; i < 4; ++i) {
      float4 wr = *(const float4*)(Wv + f * DF + jb + i * 4);
      Wt[(jb + i * 4 + 0) * DF + f] = wr.x;
      Wt[(jb + i * 4 + 1) * DF + f] = wr.y;
      Wt[(jb + i * 4 + 2) * DF + f] = wr.z;
      Wt[(jb + i * 4 + 3) * DF + f] = wr.w;
    }
  }
  const float4 b4 = *(const float4*)(bv + f0);

  int t = blockIdx.x;
  stage_tile(xs[0], x, t * PTILE, wave, lane);
  asm volatile("s_waitcnt vmcnt(0) lgkmcnt(0)" ::: "memory");
  __builtin_amdgcn_s_barrier();
  asm volatile("" ::: "memory");

  int cur = 0;
  for (; t < NTILES; t += GBLK) {
    const int pbase = t * PTILE;
    stage_tile(xs[cur ^ 1], x, (t + GBLK) * PTILE, wave, lane);
    int4 c4;
    {
      const int cb = pbase + pg * 4;
      if (cb + 3 < NPTS) {
        c4 = *(const int4*)(cluster + cb);
      } else {
        c4.x = cluster[cb + 0 < NPTS ? cb + 0 : NPTS - 1];
        c4.y = cluster[cb + 1 < NPTS ? cb + 1 : NPTS - 1];
        c4.z = cluster[cb + 2 < NPTS ? cb + 2 : NPTS - 1];
        c4.w = cluster[cb + 3 < NPTS ? cb + 3 : NPTS - 1];
      }
    }
    asm volatile("" ::: "memory");

    float4 acc[4];
#pragma unroll
    for (int pp = 0; pp < 4; ++pp) acc[pp] = b4;
#pragma unroll 4
    for (int j4 = 0; j4 < 16; ++j4) {
      float4 wv[4];
#pragma unroll
      for (int e = 0; e < 4; ++e)
        wv[e] = *(const float4*)(Wt + (j4 * 4 + e) * DF + f0);
      const int xoff = (j4 ^ pg) * 4;
#pragma unroll
      for (int pp = 0; pp < 4; ++pp) {
        float4 xv = *(const float4*)(&xs[cur][(pg * 4 + pp) * DF + xoff]);
        acc[pp].x = fmaf(xv.x, wv[0].x, acc[pp].x);
        acc[pp].y = fmaf(xv.x, wv[0].y, acc[pp].y);
        acc[pp].z = fmaf(xv.x, wv[0].z, acc[pp].z);
        acc[pp].w = fmaf(xv.x, wv[0].w, acc[pp].w);
        acc[pp].x = fmaf(xv.y, wv[1].x, acc[pp].x);
        acc[pp].y = fmaf(xv.y, wv[1].y, acc[pp].y);
        acc[pp].z = fmaf(xv.y, wv[1].z, acc[pp].z);
        acc[pp].w = fmaf(xv.y, wv[1].w, acc[pp].w);
        acc[pp].x = fmaf(xv.z, wv[2].x, acc[pp].x);
        acc[pp].y = fmaf(xv.z, wv[2].y, acc[pp].y);
        acc[pp].z = fmaf(xv.z, wv[2].z, acc[pp].z);
        acc[pp].w = fmaf(xv.z, wv[2].w, acc[pp].w);
        acc[pp].x = fmaf(xv.w, wv[3].x, acc[pp].x);
        acc[pp].y = fmaf(xv.w, wv[3].y, acc[pp].y);
        acc[pp].z = fmaf(xv.w, wv[3].z, acc[pp].z);
        acc[pp].w = fmaf(xv.w, wv[3].w, acc[pp].w);
      }
    }

    // ---- epilogue: raw v store + fused M (x from LDS, g from L2) ----
#pragma unroll
    for (int pp = 0; pp < 4; ++pp) {
      const int p = pbase + pg * 4 + pp;
      if (p < NPTS) {
        const int cc = (pp == 0) ? c4.x : (pp == 1) ? c4.y
                       : (pp == 2) ? c4.z : c4.w;
        *(float4*)(out + (size_t)p * DF + f0) = acc[pp];
        // M partial over features f0..f0+3; x chunk fg at swizzled slot fg^pg
        const float4 xv =
            *(const float4*)(&xs[cur][(pg * 4 + pp) * DF + ((fg ^ pg) << 2)]);
        const float4 gv = *(const float4*)(gtab + (size_t)cc * DF + f0);
        float m = xv.x * gv.x + xv.y * gv.y + xv.z * gv.z + xv.w * gv.w;
        m += __shfl_xor(m, 1, 64);
        m += __shfl_xor(m, 2, 64);
        m += __shfl_xor(m, 4, 64);
        m += __shfl_xor(m, 8, 64);
        if (fg == 0) {
          const float M = m + bdot[cc];
          Mv[p] = M;
          const unsigned e = f2o(M);
          unsigned* mm = mmax_u + cc;
          if (e > *mm) atomicMax(mm, e);
        }
      }
    }

    asm volatile("s_waitcnt vmcnt(0)" ::: "memory");
    __builtin_amdgcn_s_barrier();
    asm volatile("" ::: "memory");
    cur ^= 1;
  }
}

// e = exp(M - mmax[c]); Mv <- e (overwrite); denom[c] += e.
__global__ void denom_kernel(float* __restrict__ Mv,
                             const int* __restrict__ cluster,
                             const unsigned* __restrict__ mmax_u,
                             float* __restrict__ denom) {
  int i = blockIdx.x * blockDim.x + threadIdx.x;
  if (i < NPTS) {
    int c = cluster[i];
    const float e = __expf(Mv[i] - o2f(mmax_u[c]));
    Mv[i] = e;
    atomicAdd(denom + c, e);
  }
}

// ---------------------------------------------------------------------------
// BN stats over h = attn*v (streaming v); also materializes attn[p] (2 MB)
// so the apply pass needs no gather chain at all.
// ---------------------------------------------------------------------------
__launch_bounds__(TPB)
__global__ void stats_kernel(const float* __restrict__ v,
                             const int* __restrict__ cluster,
                             const float* __restrict__ e_of_p,  // = Mv
                             const float* __restrict__ denom,
                             float* __restrict__ attn_out,
                             float* __restrict__ sums) {
  __shared__ float red[2048];
  const int tid = threadIdx.x;
  const int fg = tid & 15;
  const int pg = tid >> 4;
  const int f0 = fg * 4;
  float4 s1 = make_float4(0.f, 0.f, 0.f, 0.f);
  float4 s2 = make_float4(0.f, 0.f, 0.f, 0.f);
  for (int t = blockIdx.x; t < NTILES; t += gridDim.x) {
    const int pbase = t * PTILE;
#pragma unroll
    for (int pp = 0; pp < 4; ++pp) {
      const int p = pbase + pg * 4 + pp;
      if (p < NPTS) {
        const int cc = cluster[p];
        const float attn = e_of_p[p] / denom[cc];
        if (fg == 0) attn_out[p] = attn;
        const float4 vv = *(const float4*)(v + (size_t)p * DF + f0);
        const float hx = attn * vv.x, hy = attn * vv.y;
        const float hz = attn * vv.z, hw = attn * vv.w;
        s1.x += hx; s1.y += hy; s1.z += hz; s1.w += hw;
        s2.x += hx * hx; s2.y += hy * hy; s2.z += hz * hz; s2.w += hw * hw;
      }
    }
  }
  *(float4*)(red + pg * DF + f0) = s1;
  *(float4*)(red + 1024 + pg * DF + f0) = s2;
  __syncthreads();
  if (tid < DF) {
    float a = 0.f, b = 0.f;
#pragma unroll
    for (int g = 0; g < 16; ++g) {
      a += red[g * DF + tid];
      b += red[1024 + g * DF + tid];
    }
    atomicAdd(sums + tid, a);
    atomicAdd(sums + DF + tid, b);
  }
}

__global__ void finalize_kernel(const float* __restrict__ sums,
                                const float* __restrict__ gamma,
                                const float* __restrict__ beta,
                                float* __restrict__ scale,
                                float* __restrict__ shift) {
  int d = threadIdx.x;
  float mean = sums[d] * (1.0f / NPTS);
  float var = sums[DF + d] * (1.0f / NPTS) - mean * mean;
  float s = gamma[d] * rsqrtf(var + BN_EPS);
  scale[d] = s;
  shift[d] = fmaf(-mean, s, beta[d]);
}

// out = relu((attn*v)*scale + shift), in place; attn pre-materialized.
__global__ void apply_kernel(float* __restrict__ out,
                             const float* __restrict__ attn_in,
                             const float* __restrict__ scale,
                             const float* __restrict__ shift) {
  const int g0 = blockIdx.x * TPB + threadIdx.x;
  const int c = g0 & 15;  // column float4-chunk (stride preserves it)
  const float4 sc = *(const float4*)(scale + c * 4);
  const float4 sh = *(const float4*)(shift + c * 4);
  const int stride = SBLK * TPB;
  for (int idx = g0; idx < NPTS * 16; idx += stride) {
    const int r = idx >> 4;
    const float attn = attn_in[r];
    float4* p = (float4*)out + idx;
    float4 v = *p;
    v.x = fmaxf(fmaf(attn * v.x, sc.x, sh.x), 0.f);
    v.y = fmaxf(fmaf(attn * v.y, sc.y, sh.y), 0.f);
    v.z = fmaxf(fmaf(attn * v.z, sc.z, sh.z), 0.f);
    v.w = fmaxf(fmaf(attn * v.w, sc.w, sh.w), 0.f);
    *p = v;
  }
}

extern "C" void kernel_launch(void* const* d_in, const int* in_sizes, int n_in,
                              void* d_out, int out_size, void* d_ws,
                              size_t ws_size, hipStream_t stream) {
  const float* x = (const float*)d_in[1];
  const int* cluster = (const int*)d_in[2];
  const float* Wv = (const float*)d_in[3];
  const float* bv = (const float*)d_in[4];
  const float* Wk = (const float*)d_in[5];
  const float* bk = (const float*)d_in[6];
  const float* Wq = (const float*)d_in[7];
  const float* bq = (const float*)d_in[8];
  const float* gamma = (const float*)d_in[9];
  const float* beta = (const float*)d_in[10];
  float* out = (float*)d_out;

  float* ws = (float*)d_ws;
  unsigned* q_u = (unsigned*)ws;      // dead after g_kernel
  float* attn = ws;                   // aliases q_u (stats writes, apply reads)
  unsigned* mmax_u = (unsigned*)(ws + 640000);
  float* denom = ws + 650000;
  float* sums = ws + 660000;
  float* scale = ws + 660128;
  float* shift = ws + 660192;
  float* Mv = ws + 660256;
  float* gtab = ws + 1160256;   // [NC*DF]
  float* bdot = ws + 1800256;   // [NC]

  // zero q_u / mmax_u / denom / sums (0u == sortable "-inf" sentinel)
  hipMemsetAsync(d_ws, 0, 660256 * sizeof(float), stream);

  // 1) Q projection -> q_u segment-max
  q_kernel<<<GBLK, TPB, 0, stream>>>(x, cluster, Wq, bq, q_u);
  // 2) per-cluster g = Wk^T q, b = bk.q
  g_kernel<<<(NC + 3) / 4, TPB, 0, stream>>>(q_u, Wk, bk, gtab, bdot);
  // 3) V projection + fused M (x from LDS) -> v in out, Mv, mmax
  vm_kernel<<<GBLK, TPB, 0, stream>>>(x, cluster, Wv, bv, gtab, bdot, Mv,
                                      mmax_u, out);
  // 4) e = exp(M-mmax) (stored into Mv), denom = segment sum
  denom_kernel<<<(NPTS + 255) / 256, 256, 0, stream>>>(Mv, cluster, mmax_u,
                                                       denom);
  // 5) BN stats over h = attn*v; materialize attn[p]
  stats_kernel<<<SBLK, TPB, 0, stream>>>(out, cluster, Mv, denom, attn, sums);
  // 6) BN scale/shift
  finalize_kernel<<<1, 64, 0, stream>>>(sums, gamma, beta, scale, shift);
  // 7) apply attn + bn + relu in place (no gathers)
  apply_kernel<<<SBLK, TPB, 0, stream>>>(out, attn, scale, shift);
}